// Round 3
// baseline (250.825 us; speedup 1.0000x reference)
//
#include <hip/hip_runtime.h>
#include <hip/hip_bf16.h>

// Problem constants (B=2, T=2048, C=1024, H=16, hd=64)
#define TT    2048
#define CC    1024
#define N3C   3072
#define MROWS 4096   // B*T

typedef __attribute__((ext_vector_type(8))) short short8;
typedef __attribute__((ext_vector_type(4))) float floatx4;

static __device__ __forceinline__ unsigned short f2bf(float f) {
  union { float f; unsigned u; } v; v.f = f;
  return (unsigned short)((v.u + 0x7fffu + ((v.u >> 16) & 1u)) >> 16);
}

// ---------------- transpose W1 [1024][3072] -> W1t bf16 [3072][1024] ----------------
__global__ __launch_bounds__(256) void k_tr_w1(const float* __restrict__ w,
                                               unsigned short* __restrict__ wt) {
  __shared__ float tile[32][33];
  int k0 = blockIdx.x * 32;   // over K=1024
  int n0 = blockIdx.y * 32;   // over N=3072
  int tx = threadIdx.x & 31;
  int ty = threadIdx.x >> 5;  // 0..7
#pragma unroll
  for (int j = 0; j < 4; ++j)
    tile[ty + 8 * j][tx] = w[(size_t)(k0 + ty + 8 * j) * N3C + n0 + tx];
  __syncthreads();
#pragma unroll
  for (int j = 0; j < 4; ++j)
    wt[(size_t)(n0 + ty + 8 * j) * CC + k0 + tx] = f2bf(tile[tx][ty + 8 * j]);
}

// ---------------- QKV GEMM: x[4096,1024](f32) x W1t + b1 -> qkv bf16 ----------------
// 128x128 tile, BK=64, 4 waves (each 64x64). A reg-staged (f32->bf16), B via global_load_lds.
__global__ __launch_bounds__(256) void k_qkv_gemm(const float* __restrict__ x,
                                                  const unsigned short* __restrict__ wt,
                                                  const float* __restrict__ b1,
                                                  unsigned short* __restrict__ qkv) {
  __shared__ unsigned short lA[128 * 64];
  __shared__ unsigned short lB[128 * 64];
  const int tid = threadIdx.x;
  const int bm = blockIdx.x;       // 0..31
  const int bn = blockIdx.y;       // 0..23
  const int wid = tid >> 6, lane = tid & 63;
  const int wr = wid >> 1, wc = wid & 1;
  const int lr = lane & 15;
  const int lg = lane >> 4;
  const int lk = lg * 8;

  floatx4 acc[4][4] = {};

  for (int kt = 0; kt < CC; kt += 64) {
#pragma unroll
    for (int c = 0; c < 4; ++c) {
      int eo = c * 2048 + tid * 8;         // element offset in [128][64] tile
      int row = eo >> 6, col = eo & 63;
      // A: read f32 x, convert, ds_write_b128
      const float* gx = x + (size_t)(bm * 128 + row) * CC + kt + col;
      float4 f0 = *reinterpret_cast<const float4*>(gx);
      float4 f1 = *reinterpret_cast<const float4*>(gx + 4);
      short8 pk;
      pk[0] = (short)f2bf(f0.x); pk[1] = (short)f2bf(f0.y);
      pk[2] = (short)f2bf(f0.z); pk[3] = (short)f2bf(f0.w);
      pk[4] = (short)f2bf(f1.x); pk[5] = (short)f2bf(f1.y);
      pk[6] = (short)f2bf(f1.z); pk[7] = (short)f2bf(f1.w);
      *reinterpret_cast<short8*>(lA + eo) = pk;
      // B: async global->LDS
      const unsigned short* gb = wt + (size_t)(bn * 128 + row) * CC + kt + col;
      __builtin_amdgcn_global_load_lds((const __attribute__((address_space(1))) void*)gb,
                                       (__attribute__((address_space(3))) void*)(lB + eo), 16, 0, 0);
    }
    __syncthreads();
#pragma unroll
    for (int ks = 0; ks < 2; ++ks) {
      short8 a[4], b[4];
#pragma unroll
      for (int m = 0; m < 4; ++m)
        a[m] = *reinterpret_cast<const short8*>(lA + (wr * 64 + m * 16 + lr) * 64 + ks * 32 + lk);
#pragma unroll
      for (int n = 0; n < 4; ++n)
        b[n] = *reinterpret_cast<const short8*>(lB + (wc * 64 + n * 16 + lr) * 64 + ks * 32 + lk);
#pragma unroll
      for (int m = 0; m < 4; ++m)
#pragma unroll
        for (int n = 0; n < 4; ++n)
          acc[m][n] = __builtin_amdgcn_mfma_f32_16x16x32_bf16(a[m], b[n], acc[m][n], 0, 0, 0);
    }
    __syncthreads();
  }

  const int rowb = bm * 128 + wr * 64;
  const int colb = bn * 128 + wc * 64;
#pragma unroll
  for (int n = 0; n < 4; ++n) {
    int col = colb + n * 16 + lr;
    float bias = b1[col];
#pragma unroll
    for (int m = 0; m < 4; ++m)
#pragma unroll
      for (int r = 0; r < 4; ++r) {
        int row = rowb + m * 16 + lg * 4 + r;
        qkv[(size_t)row * N3C + col] = f2bf(acc[m][n][r] + bias);
      }
  }
}

// ---------------- Flash attention: qkv bf16 -> sdp f32 [4096][1024] (in d_out) ----------------
// block = 64 q-rows of one (b,h); 4 waves x 16 rows; KV tiles of 64.
__global__ __launch_bounds__(256) void k_attn(const unsigned short* __restrict__ qkv,
                                              float* __restrict__ sdp) {
  __shared__ unsigned short lK[64 * 64];
  __shared__ unsigned short lVt[64 * 64];   // transposed: [hd][key]
  __shared__ unsigned short lP[4][16 * 64];

  const int tid = threadIdx.x;
  const int lane = tid & 63, wid = tid >> 6;
  const int lr = lane & 15;
  const int lg = lane >> 4;
  const int lk = lg * 8;

  const int bid = blockIdx.x;
  const int qb = bid & 31;
  const int h  = (bid >> 5) & 15;
  const int b  = bid >> 9;

  const int qrow0 = qb * 64 + wid * 16;
  const size_t qbase = ((size_t)(b * TT + qrow0 + lr)) * N3C + h * 64;

  short8 aq[2];
  aq[0] = *reinterpret_cast<const short8*>(qkv + qbase + lk);
  aq[1] = *reinterpret_cast<const short8*>(qkv + qbase + 32 + lk);

  floatx4 o[4] = {};
  float mrow[4] = {-1e30f, -1e30f, -1e30f, -1e30f};
  float lrow[4] = {0.f, 0.f, 0.f, 0.f};

  for (int ktile = 0; ktile < TT / 64; ++ktile) {
    // stage K tile [64 keys][64 hd] via global_load_lds
#pragma unroll
    for (int c = 0; c < 2; ++c) {
      int eo = c * 2048 + tid * 8;
      int row = eo >> 6, col = eo & 63;
      const unsigned short* g =
          qkv + ((size_t)(b * TT + ktile * 64 + row)) * N3C + CC + h * 64 + col;
      __builtin_amdgcn_global_load_lds((const __attribute__((address_space(1))) void*)g,
                                       (__attribute__((address_space(3))) void*)(lK + eo), 16, 0, 0);
    }
    // stage V transposed (manual): each thread reads 16 bf16 of one V row
    {
      int row = tid >> 2;
      int colb = (tid & 3) * 16;
      const unsigned short* g =
          qkv + ((size_t)(b * TT + ktile * 64 + row)) * N3C + 2 * CC + h * 64 + colb;
      short8 v0 = *reinterpret_cast<const short8*>(g);
      short8 v1 = *reinterpret_cast<const short8*>(g + 8);
#pragma unroll
      for (int j = 0; j < 8; ++j) lVt[(colb + j) * 64 + row] = (unsigned short)v0[j];
#pragma unroll
      for (int j = 0; j < 8; ++j) lVt[(colb + 8 + j) * 64 + row] = (unsigned short)v1[j];
    }
    __syncthreads();

    // S = Q K^T, per wave 16 q-rows x 64 keys
    floatx4 s[4];
#pragma unroll
    for (int n = 0; n < 4; ++n) {
      floatx4 z = {};
#pragma unroll
      for (int ks = 0; ks < 2; ++ks) {
        short8 bk = *reinterpret_cast<const short8*>(lK + (n * 16 + lr) * 64 + ks * 32 + lk);
        z = __builtin_amdgcn_mfma_f32_16x16x32_bf16(aq[ks], bk, z, 0, 0, 0);
      }
      s[n] = z;
    }
    const float sc = 0.03125f;  // 1/sqrt(1024) — module scales by d_model
#pragma unroll
    for (int n = 0; n < 4; ++n)
#pragma unroll
      for (int r = 0; r < 4; ++r) s[n][r] *= sc;

    // online softmax (C-layout: row q = lg*4+r, col key = n*16+lr; reduce over lane&15)
    float alpha[4], p[4][4];
#pragma unroll
    for (int r = 0; r < 4; ++r) {
      float v = fmaxf(fmaxf(s[0][r], s[1][r]), fmaxf(s[2][r], s[3][r]));
#pragma unroll
      for (int msk = 1; msk <= 8; msk <<= 1) v = fmaxf(v, __shfl_xor(v, msk));
      float mnew = fmaxf(mrow[r], v);
      alpha[r] = __expf(mrow[r] - mnew);
      mrow[r] = mnew;
      float acc_ = 0.f;
#pragma unroll
      for (int n = 0; n < 4; ++n) {
        p[n][r] = __expf(s[n][r] - mnew);
        acc_ += p[n][r];
      }
#pragma unroll
      for (int msk = 1; msk <= 8; msk <<= 1) acc_ += __shfl_xor(acc_, msk);
      lrow[r] = lrow[r] * alpha[r] + acc_;
    }
#pragma unroll
    for (int n = 0; n < 4; ++n)
#pragma unroll
      for (int r = 0; r < 4; ++r) o[n][r] *= alpha[r];

    // P (C-layout) -> LDS -> A-layout fragments
#pragma unroll
    for (int n = 0; n < 4; ++n)
#pragma unroll
      for (int r = 0; r < 4; ++r)
        lP[wid][(lg * 4 + r) * 64 + n * 16 + lr] = f2bf(p[n][r]);
    __syncthreads();

    short8 ap[2];
    ap[0] = *reinterpret_cast<const short8*>(lP[wid] + lr * 64 + lk);
    ap[1] = *reinterpret_cast<const short8*>(lP[wid] + lr * 64 + 32 + lk);
#pragma unroll
    for (int ks = 0; ks < 2; ++ks)
#pragma unroll
      for (int n = 0; n < 4; ++n) {
        short8 bv = *reinterpret_cast<const short8*>(lVt + (n * 16 + lr) * 64 + ks * 32 + lk);
        o[n] = __builtin_amdgcn_mfma_f32_16x16x32_bf16(ap[ks], bv, o[n], 0, 0, 0);
      }
    __syncthreads();  // protect lK/lVt before next stage
  }

  // epilogue: normalize, write merged-head sdp (f32, into d_out scratch)
  float linv[4];
#pragma unroll
  for (int r = 0; r < 4; ++r) linv[r] = 1.0f / lrow[r];
  const int orow0 = b * TT + qrow0;
#pragma unroll
  for (int n = 0; n < 4; ++n)
#pragma unroll
    for (int r = 0; r < 4; ++r)
      sdp[(size_t)(orow0 + lg * 4 + r) * CC + h * 64 + n * 16 + lr] = o[n][r] * linv[r];
}

// ---------------- residual + LayerNorm, in-place on io (f32 sdp -> f32 out) ----------------
__global__ __launch_bounds__(256) void k_ln(const float* __restrict__ x,
                                            const float* __restrict__ gamma,
                                            const float* __restrict__ beta,
                                            float* io) {
  __shared__ float red[2][4];
  const int row = blockIdx.x;
  const int tid = threadIdx.x;
  const int i0 = tid * 4;
  float4 xv = *reinterpret_cast<const float4*>(x + (size_t)row * CC + i0);
  float4 sv = *reinterpret_cast<const float4*>(io + (size_t)row * CC + i0);
  float y[4] = {xv.x + sv.x, xv.y + sv.y, xv.z + sv.z, xv.w + sv.w};
  float s = y[0] + y[1] + y[2] + y[3];
  float s2 = y[0] * y[0] + y[1] * y[1] + y[2] * y[2] + y[3] * y[3];
#pragma unroll
  for (int msk = 1; msk < 64; msk <<= 1) {
    s += __shfl_xor(s, msk);
    s2 += __shfl_xor(s2, msk);
  }
  const int wid = tid >> 6;
  if ((tid & 63) == 0) { red[0][wid] = s; red[1][wid] = s2; }
  __syncthreads();
  s = red[0][0] + red[0][1] + red[0][2] + red[0][3];
  s2 = red[1][0] + red[1][1] + red[1][2] + red[1][3];
  float mean = s * (1.0f / CC);
  float var = s2 * (1.0f / CC) - mean * mean;
  float rstd = rsqrtf(var + 1e-6f);
  float4 r;
  r.x = (y[0] - mean) * rstd * gamma[i0 + 0] + beta[i0 + 0];
  r.y = (y[1] - mean) * rstd * gamma[i0 + 1] + beta[i0 + 1];
  r.z = (y[2] - mean) * rstd * gamma[i0 + 2] + beta[i0 + 2];
  r.w = (y[3] - mean) * rstd * gamma[i0 + 3] + beta[i0 + 3];
  *reinterpret_cast<float4*>(io + (size_t)row * CC + i0) = r;
}

extern "C" void kernel_launch(void* const* d_in, const int* in_sizes, int n_in,
                              void* d_out, int out_size, void* d_ws, size_t ws_size,
                              hipStream_t stream) {
  const float* x     = (const float*)d_in[0];
  const float* W1    = (const float*)d_in[1];
  const float* b1    = (const float*)d_in[2];
  const float* gamma = (const float*)d_in[3];
  const float* beta  = (const float*)d_in[4];

  // Memory plan: qkv bf16 (25.2 MB) is the ONLY d_ws user.
  // d_out (f32, 16.78 MB) doubles as scratch: first W1t bf16 (6.3 MB, dead
  // after the GEMM), then sdp f32 (16.78 MB — fully overwritten by k_attn),
  // then LayerNorm runs in-place. Output dtype is FLOAT32 (reference is f32).
  unsigned short* qkv = (unsigned short*)d_ws;
  unsigned short* w1t = (unsigned short*)d_out;
  float*          sdp = (float*)d_out;

  k_tr_w1<<<dim3(CC / 32, N3C / 32), 256, 0, stream>>>(W1, w1t);
  k_qkv_gemm<<<dim3(MROWS / 128, N3C / 128), 256, 0, stream>>>(x, w1t, b1, qkv);
  k_attn<<<2 * 16 * (TT / 64), 256, 0, stream>>>(qkv, sdp);
  k_ln<<<MROWS, 256, 0, stream>>>(x, gamma, beta, sdp);
}

// Round 4
// 218.679 us; speedup vs baseline: 1.1470x; 1.1470x over previous
//
#include <hip/hip_runtime.h>
#include <hip/hip_bf16.h>

// Problem constants (B=2, T=2048, C=1024, H=16, hd=64)
#define TT    2048
#define CC    1024
#define N3C   3072
#define MROWS 4096   // B*T

typedef __attribute__((ext_vector_type(8))) short short8;
typedef __attribute__((ext_vector_type(4))) float floatx4;

static __device__ __forceinline__ unsigned short f2bf(float f) {
  union { float f; unsigned u; } v; v.f = f;
  return (unsigned short)((v.u + 0x7fffu + ((v.u >> 16) & 1u)) >> 16);
}

// ---------------- transpose W1 [1024][3072] -> W1t bf16 [3072][1024] ----------------
__global__ __launch_bounds__(256) void k_tr_w1(const float* __restrict__ w,
                                               unsigned short* __restrict__ wt) {
  __shared__ float tile[32][33];
  int k0 = blockIdx.x * 32;   // over K=1024
  int n0 = blockIdx.y * 32;   // over N=3072
  int tx = threadIdx.x & 31;
  int ty = threadIdx.x >> 5;  // 0..7
#pragma unroll
  for (int j = 0; j < 4; ++j)
    tile[ty + 8 * j][tx] = w[(size_t)(k0 + ty + 8 * j) * N3C + n0 + tx];
  __syncthreads();
#pragma unroll
  for (int j = 0; j < 4; ++j)
    wt[(size_t)(n0 + ty + 8 * j) * CC + k0 + tx] = f2bf(tile[tx][ty + 8 * j]);
}

// ---------------- QKV GEMM: x[4096,1024](f32) x W1t + b1 -> qkv bf16 ----------------
// 128x128 tile, BK=64, 4 waves (each 64x64). A reg-staged (f32->bf16), B via global_load_lds.
__global__ __launch_bounds__(256) void k_qkv_gemm(const float* __restrict__ x,
                                                  const unsigned short* __restrict__ wt,
                                                  const float* __restrict__ b1,
                                                  unsigned short* __restrict__ qkv) {
  __shared__ unsigned short lA[128 * 64];
  __shared__ unsigned short lB[128 * 64];
  const int tid = threadIdx.x;
  const int bm = blockIdx.x;       // 0..31
  const int bn = blockIdx.y;       // 0..23
  const int wid = tid >> 6, lane = tid & 63;
  const int wr = wid >> 1, wc = wid & 1;
  const int lr = lane & 15;
  const int lg = lane >> 4;
  const int lk = lg * 8;

  floatx4 acc[4][4] = {};

  for (int kt = 0; kt < CC; kt += 64) {
#pragma unroll
    for (int c = 0; c < 4; ++c) {
      int eo = c * 2048 + tid * 8;         // element offset in [128][64] tile
      int row = eo >> 6, col = eo & 63;
      // A: read f32 x, convert, ds_write_b128
      const float* gx = x + (size_t)(bm * 128 + row) * CC + kt + col;
      float4 f0 = *reinterpret_cast<const float4*>(gx);
      float4 f1 = *reinterpret_cast<const float4*>(gx + 4);
      short8 pk;
      pk[0] = (short)f2bf(f0.x); pk[1] = (short)f2bf(f0.y);
      pk[2] = (short)f2bf(f0.z); pk[3] = (short)f2bf(f0.w);
      pk[4] = (short)f2bf(f1.x); pk[5] = (short)f2bf(f1.y);
      pk[6] = (short)f2bf(f1.z); pk[7] = (short)f2bf(f1.w);
      *reinterpret_cast<short8*>(lA + eo) = pk;
      // B: async global->LDS
      const unsigned short* gb = wt + (size_t)(bn * 128 + row) * CC + kt + col;
      __builtin_amdgcn_global_load_lds((const __attribute__((address_space(1))) void*)gb,
                                       (__attribute__((address_space(3))) void*)(lB + eo), 16, 0, 0);
    }
    __syncthreads();
#pragma unroll
    for (int ks = 0; ks < 2; ++ks) {
      short8 a[4], b[4];
#pragma unroll
      for (int m = 0; m < 4; ++m)
        a[m] = *reinterpret_cast<const short8*>(lA + (wr * 64 + m * 16 + lr) * 64 + ks * 32 + lk);
#pragma unroll
      for (int n = 0; n < 4; ++n)
        b[n] = *reinterpret_cast<const short8*>(lB + (wc * 64 + n * 16 + lr) * 64 + ks * 32 + lk);
#pragma unroll
      for (int m = 0; m < 4; ++m)
#pragma unroll
        for (int n = 0; n < 4; ++n)
          acc[m][n] = __builtin_amdgcn_mfma_f32_16x16x32_bf16(a[m], b[n], acc[m][n], 0, 0, 0);
    }
    __syncthreads();
  }

  const int rowb = bm * 128 + wr * 64;
  const int colb = bn * 128 + wc * 64;
#pragma unroll
  for (int n = 0; n < 4; ++n) {
    int col = colb + n * 16 + lr;
    float bias = b1[col];
#pragma unroll
    for (int m = 0; m < 4; ++m)
#pragma unroll
      for (int r = 0; r < 4; ++r) {
        int row = rowb + m * 16 + lg * 4 + r;
        qkv[(size_t)row * N3C + col] = f2bf(acc[m][n][r] + bias);
      }
  }
}

// ---------------- Flash attention: qkv bf16 -> sdp f32 [4096][1024] (in d_out) ----------------
// block = 64 q-rows of one (b,h); 4 waves x 16 rows; KV tiles of 64.
// All LDS tiles XOR-swizzled: el(row,col) = row*64 + (col ^ ((row&7)<<3)).
// K staged via global_load_lds with pre-swizzled GLOBAL source (linear LDS dest).
// Double-buffered K/V: stage t+1 before compute t; one barrier per tile.
__global__ __launch_bounds__(256) void k_attn(const unsigned short* __restrict__ qkv,
                                              float* __restrict__ sdp) {
  __shared__ unsigned short lK[2][64 * 64];
  __shared__ unsigned short lVt[2][64 * 64];   // transposed: [hd][key], swizzled
  __shared__ unsigned short lP[4][16 * 64];

  const int tid = threadIdx.x;
  const int lane = tid & 63, wid = tid >> 6;
  const int lr = lane & 15;
  const int lg = lane >> 4;
  const int lk = lg * 8;
  const int swm = (lr & 7) << 3;   // read-side swizzle mask (row&7 == lr&7 for row=n*16+lr)

  const int bid = blockIdx.x;
  const int qb = bid & 31;
  const int h  = (bid >> 5) & 15;
  const int b  = bid >> 9;

  const int qrow0 = qb * 64 + wid * 16;
  const size_t qbase = ((size_t)(b * TT + qrow0 + lr)) * N3C + h * 64;

  short8 aq[2];
  aq[0] = *reinterpret_cast<const short8*>(qkv + qbase + lk);
  aq[1] = *reinterpret_cast<const short8*>(qkv + qbase + 32 + lk);

  floatx4 o[4] = {};
  float mrow[4] = {-1e30f, -1e30f, -1e30f, -1e30f};
  float lrow[4] = {0.f, 0.f, 0.f, 0.f};

  // K staging geometry: 2 chunks x 256 threads x 8 elements = 64x64 tile
  const int keo0 = tid * 8;
  const int krow0 = keo0 >> 6, kcol0 = (keo0 & 63) ^ ((krow0 & 7) << 3);
  const int keo1 = 2048 + tid * 8;
  const int krow1 = keo1 >> 6, kcol1 = (keo1 & 63) ^ ((krow1 & 7) << 3);
  const size_t kbase = (size_t)(b * TT) * N3C + CC + h * 64;

  // V staging geometry: thread handles V[key=tid>>2][hd = (tid&3)*16 .. +16]
  const int vrow = tid >> 2;
  const int vcolb = (tid & 3) * 16;
  const size_t vbase = ((size_t)(b * TT + vrow)) * N3C + 2 * CC + h * 64 + vcolb;

  // ---- prologue: stage tile 0 ----
  {
    const unsigned short* g0 = qkv + kbase + (size_t)krow0 * N3C + kcol0;
    __builtin_amdgcn_global_load_lds((const __attribute__((address_space(1))) void*)g0,
                                     (__attribute__((address_space(3))) void*)(&lK[0][0] + keo0), 16, 0, 0);
    const unsigned short* g1 = qkv + kbase + (size_t)krow1 * N3C + kcol1;
    __builtin_amdgcn_global_load_lds((const __attribute__((address_space(1))) void*)g1,
                                     (__attribute__((address_space(3))) void*)(&lK[0][0] + keo1), 16, 0, 0);
    short8 v0 = *reinterpret_cast<const short8*>(qkv + vbase);
    short8 v1 = *reinterpret_cast<const short8*>(qkv + vbase + 8);
#pragma unroll
    for (int j = 0; j < 8; ++j) {
      int rr = vcolb + j;
      lVt[0][rr * 64 + (vrow ^ ((rr & 7) << 3))] = (unsigned short)v0[j];
    }
#pragma unroll
    for (int j = 0; j < 8; ++j) {
      int rr = vcolb + 8 + j;
      lVt[0][rr * 64 + (vrow ^ ((rr & 7) << 3))] = (unsigned short)v1[j];
    }
  }
  __syncthreads();

  for (int kt = 0; kt < TT / 64; ++kt) {
    const int cur = kt & 1;
    short8 nv0, nv1;
    if (kt < TT / 64 - 1) {
      // issue next tile's K stage (async to LDS) + V loads (to regs)
      const size_t koff = kbase + (size_t)((kt + 1) * 64) * N3C;
      const unsigned short* g0 = qkv + koff + (size_t)krow0 * N3C + kcol0;
      __builtin_amdgcn_global_load_lds((const __attribute__((address_space(1))) void*)g0,
                                       (__attribute__((address_space(3))) void*)(&lK[cur ^ 1][0] + keo0), 16, 0, 0);
      const unsigned short* g1 = qkv + koff + (size_t)krow1 * N3C + kcol1;
      __builtin_amdgcn_global_load_lds((const __attribute__((address_space(1))) void*)g1,
                                       (__attribute__((address_space(3))) void*)(&lK[cur ^ 1][0] + keo1), 16, 0, 0);
      const unsigned short* gv = qkv + vbase + (size_t)((kt + 1) * 64) * N3C;
      nv0 = *reinterpret_cast<const short8*>(gv);
      nv1 = *reinterpret_cast<const short8*>(gv + 8);
    }

    // ---- S = Q K^T, per wave 16 q-rows x 64 keys ----
    floatx4 s[4];
    __builtin_amdgcn_s_setprio(1);
#pragma unroll
    for (int n = 0; n < 4; ++n) {
      floatx4 z = {};
#pragma unroll
      for (int ks = 0; ks < 2; ++ks) {
        short8 bk = *reinterpret_cast<const short8*>(
            &lK[cur][0] + (n * 16 + lr) * 64 + ((ks * 32 + lk) ^ swm));
        z = __builtin_amdgcn_mfma_f32_16x16x32_bf16(aq[ks], bk, z, 0, 0, 0);
      }
      s[n] = z;
    }
    __builtin_amdgcn_s_setprio(0);
    const float sc = 0.03125f;  // 1/sqrt(1024) — module scales by d_model
#pragma unroll
    for (int n = 0; n < 4; ++n)
#pragma unroll
      for (int r = 0; r < 4; ++r) s[n][r] *= sc;

    // ---- online softmax (C-layout: row q = lg*4+r, col key = n*16+lr) ----
    float alpha[4], p[4][4];
#pragma unroll
    for (int r = 0; r < 4; ++r) {
      float v = fmaxf(fmaxf(s[0][r], s[1][r]), fmaxf(s[2][r], s[3][r]));
#pragma unroll
      for (int msk = 1; msk <= 8; msk <<= 1) v = fmaxf(v, __shfl_xor(v, msk));
      float mnew = fmaxf(mrow[r], v);
      alpha[r] = __expf(mrow[r] - mnew);
      mrow[r] = mnew;
      float acc_ = 0.f;
#pragma unroll
      for (int n = 0; n < 4; ++n) {
        p[n][r] = __expf(s[n][r] - mnew);
        acc_ += p[n][r];
      }
#pragma unroll
      for (int msk = 1; msk <= 8; msk <<= 1) acc_ += __shfl_xor(acc_, msk);
      lrow[r] = lrow[r] * alpha[r] + acc_;
    }
#pragma unroll
    for (int n = 0; n < 4; ++n)
#pragma unroll
      for (int r = 0; r < 4; ++r) o[n][r] *= alpha[r];

    // ---- P (C-layout) -> per-wave LDS (swizzled) -> A-layout fragments ----
    // per-wave private region: no barrier needed, lgkmcnt ordering suffices
#pragma unroll
    for (int n = 0; n < 4; ++n)
#pragma unroll
      for (int r = 0; r < 4; ++r) {
        int row = lg * 4 + r;
        lP[wid][row * 64 + ((n * 16 + lr) ^ ((row & 7) << 3))] = f2bf(p[n][r]);
      }
    short8 ap[2];
    ap[0] = *reinterpret_cast<const short8*>(lP[wid] + lr * 64 + (lk ^ swm));
    ap[1] = *reinterpret_cast<const short8*>(lP[wid] + lr * 64 + ((32 + lk) ^ swm));

    // ---- PV ----
    __builtin_amdgcn_s_setprio(1);
#pragma unroll
    for (int ks = 0; ks < 2; ++ks)
#pragma unroll
      for (int n = 0; n < 4; ++n) {
        short8 bv = *reinterpret_cast<const short8*>(
            &lVt[cur][0] + (n * 16 + lr) * 64 + ((ks * 32 + lk) ^ swm));
        o[n] = __builtin_amdgcn_mfma_f32_16x16x32_bf16(ap[ks], bv, o[n], 0, 0, 0);
      }
    __builtin_amdgcn_s_setprio(0);

    // ---- write next V tile into the other buffer, then one barrier ----
    if (kt < TT / 64 - 1) {
#pragma unroll
      for (int j = 0; j < 8; ++j) {
        int rr = vcolb + j;
        lVt[cur ^ 1][rr * 64 + (vrow ^ ((rr & 7) << 3))] = (unsigned short)nv0[j];
      }
#pragma unroll
      for (int j = 0; j < 8; ++j) {
        int rr = vcolb + 8 + j;
        lVt[cur ^ 1][rr * 64 + (vrow ^ ((rr & 7) << 3))] = (unsigned short)nv1[j];
      }
    }
    __syncthreads();  // drains vmcnt (K stage) + makes V writes visible
  }

  // epilogue: normalize, write merged-head sdp (f32, into d_out scratch)
  float linv[4];
#pragma unroll
  for (int r = 0; r < 4; ++r) linv[r] = 1.0f / lrow[r];
  const int orow0 = b * TT + qrow0;
#pragma unroll
  for (int n = 0; n < 4; ++n)
#pragma unroll
    for (int r = 0; r < 4; ++r)
      sdp[(size_t)(orow0 + lg * 4 + r) * CC + h * 64 + n * 16 + lr] = o[n][r] * linv[r];
}

// ---------------- residual + LayerNorm, in-place on io (f32 sdp -> f32 out) ----------------
__global__ __launch_bounds__(256) void k_ln(const float* __restrict__ x,
                                            const float* __restrict__ gamma,
                                            const float* __restrict__ beta,
                                            float* io) {
  __shared__ float red[2][4];
  const int row = blockIdx.x;
  const int tid = threadIdx.x;
  const int i0 = tid * 4;
  float4 xv = *reinterpret_cast<const float4*>(x + (size_t)row * CC + i0);
  float4 sv = *reinterpret_cast<const float4*>(io + (size_t)row * CC + i0);
  float y[4] = {xv.x + sv.x, xv.y + sv.y, xv.z + sv.z, xv.w + sv.w};
  float s = y[0] + y[1] + y[2] + y[3];
  float s2 = y[0] * y[0] + y[1] * y[1] + y[2] * y[2] + y[3] * y[3];
#pragma unroll
  for (int msk = 1; msk < 64; msk <<= 1) {
    s += __shfl_xor(s, msk);
    s2 += __shfl_xor(s2, msk);
  }
  const int wid = tid >> 6;
  if ((tid & 63) == 0) { red[0][wid] = s; red[1][wid] = s2; }
  __syncthreads();
  s = red[0][0] + red[0][1] + red[0][2] + red[0][3];
  s2 = red[1][0] + red[1][1] + red[1][2] + red[1][3];
  float mean = s * (1.0f / CC);
  float var = s2 * (1.0f / CC) - mean * mean;
  float rstd = rsqrtf(var + 1e-6f);
  float4 r;
  r.x = (y[0] - mean) * rstd * gamma[i0 + 0] + beta[i0 + 0];
  r.y = (y[1] - mean) * rstd * gamma[i0 + 1] + beta[i0 + 1];
  r.z = (y[2] - mean) * rstd * gamma[i0 + 2] + beta[i0 + 2];
  r.w = (y[3] - mean) * rstd * gamma[i0 + 3] + beta[i0 + 3];
  *reinterpret_cast<float4*>(io + (size_t)row * CC + i0) = r;
}

extern "C" void kernel_launch(void* const* d_in, const int* in_sizes, int n_in,
                              void* d_out, int out_size, void* d_ws, size_t ws_size,
                              hipStream_t stream) {
  const float* x     = (const float*)d_in[0];
  const float* W1    = (const float*)d_in[1];
  const float* b1    = (const float*)d_in[2];
  const float* gamma = (const float*)d_in[3];
  const float* beta  = (const float*)d_in[4];

  // Memory plan: qkv bf16 (25.2 MB) is the ONLY d_ws user.
  // d_out (f32, 16.78 MB) doubles as scratch: first W1t bf16 (6.3 MB, dead
  // after the GEMM), then sdp f32 (fully overwritten by k_attn), then
  // LayerNorm runs in-place. Output dtype is FLOAT32.
  unsigned short* qkv = (unsigned short*)d_ws;
  unsigned short* w1t = (unsigned short*)d_out;
  float*          sdp = (float*)d_out;

  k_tr_w1<<<dim3(CC / 32, N3C / 32), 256, 0, stream>>>(W1, w1t);
  k_qkv_gemm<<<dim3(MROWS / 128, N3C / 128), 256, 0, stream>>>(x, w1t, b1, qkv);
  k_attn<<<2 * 16 * (TT / 64), 256, 0, stream>>>(qkv, sdp);
  k_ln<<<MROWS, 256, 0, stream>>>(x, gamma, beta, sdp);
}

// Round 5
// 173.818 us; speedup vs baseline: 1.4430x; 1.2581x over previous
//
#include <hip/hip_runtime.h>
#include <hip/hip_bf16.h>

// Problem constants (B=2, T=2048, C=1024, H=16, hd=64)
#define TT    2048
#define CC    1024
#define N3C   3072
#define MROWS 4096   // B*T

typedef __attribute__((ext_vector_type(8))) short short8;
typedef __attribute__((ext_vector_type(4))) float floatx4;

static __device__ __forceinline__ unsigned short f2bf(float f) {
  union { float f; unsigned u; } v; v.f = f;
  return (unsigned short)((v.u + 0x7fffu + ((v.u >> 16) & 1u)) >> 16);
}

// ---------------- transpose W1 [1024][3072] -> W1t bf16 [3072][1024] ----------------
__global__ __launch_bounds__(256) void k_tr_w1(const float* __restrict__ w,
                                               unsigned short* __restrict__ wt) {
  __shared__ float tile[32][33];
  int k0 = blockIdx.x * 32;   // over K=1024
  int n0 = blockIdx.y * 32;   // over N=3072
  int tx = threadIdx.x & 31;
  int ty = threadIdx.x >> 5;  // 0..7
#pragma unroll
  for (int j = 0; j < 4; ++j)
    tile[ty + 8 * j][tx] = w[(size_t)(k0 + ty + 8 * j) * N3C + n0 + tx];
  __syncthreads();
#pragma unroll
  for (int j = 0; j < 4; ++j)
    wt[(size_t)(n0 + ty + 8 * j) * CC + k0 + tx] = f2bf(tile[tx][ty + 8 * j]);
}

// ---------------- QKV GEMM: x[4096,1024](f32) x W1t + b1 -> qkv bf16 ----------------
// 128x128 tile, BK=64, 4 waves. A reg-staged (f32->bf16), B via global_load_lds.
// Q columns (col < CC) are pre-scaled by 1/sqrt(1024) so attention skips the scale.
__global__ __launch_bounds__(256) void k_qkv_gemm(const float* __restrict__ x,
                                                  const unsigned short* __restrict__ wt,
                                                  const float* __restrict__ b1,
                                                  unsigned short* __restrict__ qkv) {
  __shared__ unsigned short lA[128 * 64];
  __shared__ unsigned short lB[128 * 64];
  const int tid = threadIdx.x;
  const int bm = blockIdx.x;       // 0..31
  const int bn = blockIdx.y;       // 0..23
  const int wid = tid >> 6, lane = tid & 63;
  const int wr = wid >> 1, wc = wid & 1;
  const int lr = lane & 15;
  const int lg = lane >> 4;
  const int lk = lg * 8;

  floatx4 acc[4][4] = {};

  for (int kt = 0; kt < CC; kt += 64) {
#pragma unroll
    for (int c = 0; c < 4; ++c) {
      int eo = c * 2048 + tid * 8;         // element offset in [128][64] tile
      int row = eo >> 6, col = eo & 63;
      const float* gx = x + (size_t)(bm * 128 + row) * CC + kt + col;
      float4 f0 = *reinterpret_cast<const float4*>(gx);
      float4 f1 = *reinterpret_cast<const float4*>(gx + 4);
      short8 pk;
      pk[0] = (short)f2bf(f0.x); pk[1] = (short)f2bf(f0.y);
      pk[2] = (short)f2bf(f0.z); pk[3] = (short)f2bf(f0.w);
      pk[4] = (short)f2bf(f1.x); pk[5] = (short)f2bf(f1.y);
      pk[6] = (short)f2bf(f1.z); pk[7] = (short)f2bf(f1.w);
      *reinterpret_cast<short8*>(lA + eo) = pk;
      const unsigned short* gb = wt + (size_t)(bn * 128 + row) * CC + kt + col;
      __builtin_amdgcn_global_load_lds((const __attribute__((address_space(1))) void*)gb,
                                       (__attribute__((address_space(3))) void*)(lB + eo), 16, 0, 0);
    }
    __syncthreads();
#pragma unroll
    for (int ks = 0; ks < 2; ++ks) {
      short8 a[4], b[4];
#pragma unroll
      for (int m = 0; m < 4; ++m)
        a[m] = *reinterpret_cast<const short8*>(lA + (wr * 64 + m * 16 + lr) * 64 + ks * 32 + lk);
#pragma unroll
      for (int n = 0; n < 4; ++n)
        b[n] = *reinterpret_cast<const short8*>(lB + (wc * 64 + n * 16 + lr) * 64 + ks * 32 + lk);
#pragma unroll
      for (int m = 0; m < 4; ++m)
#pragma unroll
        for (int n = 0; n < 4; ++n)
          acc[m][n] = __builtin_amdgcn_mfma_f32_16x16x32_bf16(a[m], b[n], acc[m][n], 0, 0, 0);
    }
    __syncthreads();
  }

  const int rowb = bm * 128 + wr * 64;
  const int colb = bn * 128 + wc * 64;
#pragma unroll
  for (int n = 0; n < 4; ++n) {
    int col = colb + n * 16 + lr;
    float bias = b1[col];
    float scl = (col < CC) ? 0.03125f : 1.0f;   // fold 1/sqrt(d_model) into Q
#pragma unroll
    for (int m = 0; m < 4; ++m)
#pragma unroll
      for (int r = 0; r < 4; ++r) {
        int row = rowb + m * 16 + lg * 4 + r;
        qkv[(size_t)row * N3C + col] = f2bf((acc[m][n][r] + bias) * scl);
      }
  }
}

// ---------------- Flash attention: qkv bf16 -> sdp f32 [4096][1024] (in d_out) ----------------
// block = 64 q-rows of one (b,h); 4 waves x 16 rows; KV tiles of 64.
// Swapped QK^T (mfma(K,Q) -> S^T): lane owns one query (q=lr), 16 key-values.
// Softmax fully per-lane + 4 shfl; P relayout in-register (cvt_pk + 16 shfl).
__global__ __launch_bounds__(256) void k_attn(const unsigned short* __restrict__ qkv,
                                              float* __restrict__ sdp) {
  __shared__ unsigned short lK[2][64 * 64];
  __shared__ unsigned short lVt[2][64 * 64];   // transposed: [hd][key], swizzled

  const int tid = threadIdx.x;
  const int lane = tid & 63, wid = tid >> 6;
  const int lr = lane & 15;
  const int lg = lane >> 4;          // 0..3
  const int lk = lg * 8;
  const int swm = (lr & 7) << 3;     // read-side swizzle mask

  const int bid = blockIdx.x;
  const int qb = bid & 31;
  const int h  = (bid >> 5) & 15;
  const int b  = bid >> 9;

  const int qrow0 = qb * 64 + wid * 16;
  const size_t qbase = ((size_t)(b * TT + qrow0 + lr)) * N3C + h * 64;

  short8 aq[2];
  aq[0] = *reinterpret_cast<const short8*>(qkv + qbase + lk);
  aq[1] = *reinterpret_cast<const short8*>(qkv + qbase + 32 + lk);

  floatx4 o[4] = {};
  float m = -1e30f, l = 0.f;   // stats for query q = lr

  // shfl source lanes for the P exchange (same lr, different lg group)
  const int srcA = ((2 * lg) & 3) * 16 + lr;
  const int srcB = ((2 * lg + 1) & 3) * 16 + lr;
  const int lg2 = lg >> 1;
  const int qown = lg * 4;                 // o-domain q base (rows qown..qown+3)
  const int statbase = (lane & 48) + qown; // lane holding stats for q=qown+r: statbase+r

  // K staging geometry (global source pre-swizzled, LDS dest linear)
  const int keo0 = tid * 8;
  const int krow0 = keo0 >> 6, kcol0 = (keo0 & 63) ^ ((krow0 & 7) << 3);
  const int keo1 = 2048 + tid * 8;
  const int krow1 = keo1 >> 6, kcol1 = (keo1 & 63) ^ ((krow1 & 7) << 3);
  const size_t kbase = (size_t)(b * TT) * N3C + CC + h * 64;

  // V staging geometry: thread handles V[key=tid>>2][hd = (tid&3)*16 .. +16]
  const int vrow = tid >> 2;
  const int vcolb = (tid & 3) * 16;
  const size_t vbase = ((size_t)(b * TT + vrow)) * N3C + 2 * CC + h * 64 + vcolb;

  // ---- prologue: stage tile 0 ----
  {
    const unsigned short* g0 = qkv + kbase + (size_t)krow0 * N3C + kcol0;
    __builtin_amdgcn_global_load_lds((const __attribute__((address_space(1))) void*)g0,
                                     (__attribute__((address_space(3))) void*)(&lK[0][0] + keo0), 16, 0, 0);
    const unsigned short* g1 = qkv + kbase + (size_t)krow1 * N3C + kcol1;
    __builtin_amdgcn_global_load_lds((const __attribute__((address_space(1))) void*)g1,
                                     (__attribute__((address_space(3))) void*)(&lK[0][0] + keo1), 16, 0, 0);
    short8 v0 = *reinterpret_cast<const short8*>(qkv + vbase);
    short8 v1 = *reinterpret_cast<const short8*>(qkv + vbase + 8);
#pragma unroll
    for (int j = 0; j < 8; ++j) {
      int rr = vcolb + j;
      lVt[0][rr * 64 + (vrow ^ ((rr & 7) << 3))] = (unsigned short)v0[j];
    }
#pragma unroll
    for (int j = 0; j < 8; ++j) {
      int rr = vcolb + 8 + j;
      lVt[0][rr * 64 + (vrow ^ ((rr & 7) << 3))] = (unsigned short)v1[j];
    }
  }
  __syncthreads();

  for (int kt = 0; kt < TT / 64; ++kt) {
    const int cur = kt & 1;
    short8 nv0, nv1;
    if (kt < TT / 64 - 1) {
      const size_t koff = kbase + (size_t)((kt + 1) * 64) * N3C;
      const unsigned short* g0 = qkv + koff + (size_t)krow0 * N3C + kcol0;
      __builtin_amdgcn_global_load_lds((const __attribute__((address_space(1))) void*)g0,
                                       (__attribute__((address_space(3))) void*)(&lK[cur ^ 1][0] + keo0), 16, 0, 0);
      const unsigned short* g1 = qkv + koff + (size_t)krow1 * N3C + kcol1;
      __builtin_amdgcn_global_load_lds((const __attribute__((address_space(1))) void*)g1,
                                       (__attribute__((address_space(3))) void*)(&lK[cur ^ 1][0] + keo1), 16, 0, 0);
      const unsigned short* gv = qkv + vbase + (size_t)((kt + 1) * 64) * N3C;
      nv0 = *reinterpret_cast<const short8*>(gv);
      nv1 = *reinterpret_cast<const short8*>(gv + 8);
    }

    // ---- S^T = K Q^T : lane holds S[key = n*16+lg*4+r][q = lr] ----
    floatx4 s[4];
    __builtin_amdgcn_s_setprio(1);
#pragma unroll
    for (int n = 0; n < 4; ++n) {
      floatx4 z = {};
#pragma unroll
      for (int ks = 0; ks < 2; ++ks) {
        short8 bk = *reinterpret_cast<const short8*>(
            &lK[cur][0] + (n * 16 + lr) * 64 + ((ks * 32 + lk) ^ swm));
        z = __builtin_amdgcn_mfma_f32_16x16x32_bf16(bk, aq[ks], z, 0, 0, 0);
      }
      s[n] = z;
    }
    __builtin_amdgcn_s_setprio(0);

    // ---- per-lane online softmax over this tile's 64 keys for q=lr ----
    float pmax = s[0][0];
#pragma unroll
    for (int n = 0; n < 4; ++n)
#pragma unroll
      for (int r = 0; r < 4; ++r) pmax = fmaxf(pmax, s[n][r]);
    pmax = fmaxf(pmax, __shfl_xor(pmax, 16));
    pmax = fmaxf(pmax, __shfl_xor(pmax, 32));

    if (__any(pmax > m + 8.0f)) {         // T13 defer-max, THR=8
      float mnew = fmaxf(m, pmax);
      float alpha = __expf(m - mnew);
      m = mnew;
      l *= alpha;
      float a0 = __shfl(alpha, statbase + 0);
      float a1 = __shfl(alpha, statbase + 1);
      float a2 = __shfl(alpha, statbase + 2);
      float a3 = __shfl(alpha, statbase + 3);
#pragma unroll
      for (int n = 0; n < 4; ++n) {
        o[n][0] *= a0; o[n][1] *= a1; o[n][2] *= a2; o[n][3] *= a3;
      }
    }

    float p[4][4], lsum = 0.f;
#pragma unroll
    for (int n = 0; n < 4; ++n)
#pragma unroll
      for (int r = 0; r < 4; ++r) {
        p[n][r] = __expf(s[n][r] - m);
        lsum += p[n][r];
      }
    lsum += __shfl_xor(lsum, 16);
    lsum += __shfl_xor(lsum, 32);
    l += lsum;

    // ---- pack P to bf16 pairs: w[n][mi] = {lo=p[n][2mi], hi=p[n][2mi+1]} ----
    unsigned w[4][2];
#pragma unroll
    for (int n = 0; n < 4; ++n)
#pragma unroll
      for (int mi = 0; mi < 2; ++mi)
        asm("v_cvt_pk_bf16_f32 %0, %1, %2"
            : "=v"(w[n][mi]) : "v"(p[n][2 * mi]), "v"(p[n][2 * mi + 1]));

    // ---- in-register transpose to A-fragment words fw[ks][jp] ----
    // lane(lg,lr) needs keys ks*32+lg*8+2jp{,+1} = w[2ks+(lg>>1)][jp&1] from lane (2lg+(jp>>1))&3
    unsigned fw[2][4] = {};
#pragma unroll
    for (int N = 0; N < 4; ++N) {
      const int ksn = N >> 1;
      const bool mine = ((N & 1) == lg2);
#pragma unroll
      for (int M = 0; M < 2; ++M) {
#pragma unroll
        for (int hh = 0; hh < 2; ++hh) {
          int g = __shfl((int)w[N][M], hh ? srcB : srcA);
          if (mine) fw[ksn][M + 2 * hh] = (unsigned)g;
        }
      }
    }
    union { unsigned u[4]; short8 v; } apc0, apc1;
#pragma unroll
    for (int j = 0; j < 4; ++j) { apc0.u[j] = fw[0][j]; apc1.u[j] = fw[1][j]; }

    // ---- PV: o[q=lg*4+r][d=n*16+lr] += P^T-frag x V^T rows ----
    __builtin_amdgcn_s_setprio(1);
#pragma unroll
    for (int n = 0; n < 4; ++n) {
      short8 bv0 = *reinterpret_cast<const short8*>(
          &lVt[cur][0] + (n * 16 + lr) * 64 + ((0 + lk) ^ swm));
      o[n] = __builtin_amdgcn_mfma_f32_16x16x32_bf16(apc0.v, bv0, o[n], 0, 0, 0);
      short8 bv1 = *reinterpret_cast<const short8*>(
          &lVt[cur][0] + (n * 16 + lr) * 64 + ((32 + lk) ^ swm));
      o[n] = __builtin_amdgcn_mfma_f32_16x16x32_bf16(apc1.v, bv1, o[n], 0, 0, 0);
    }
    __builtin_amdgcn_s_setprio(0);

    // ---- write next V tile into the other buffer, then one barrier ----
    if (kt < TT / 64 - 1) {
#pragma unroll
      for (int j = 0; j < 8; ++j) {
        int rr = vcolb + j;
        lVt[cur ^ 1][rr * 64 + (vrow ^ ((rr & 7) << 3))] = (unsigned short)nv0[j];
      }
#pragma unroll
      for (int j = 0; j < 8; ++j) {
        int rr = vcolb + 8 + j;
        lVt[cur ^ 1][rr * 64 + (vrow ^ ((rr & 7) << 3))] = (unsigned short)nv1[j];
      }
    }
    __syncthreads();  // drains vmcnt (K stage) + makes V writes visible
  }

  // epilogue: broadcast 1/l to o-domain, write merged-head sdp (f32)
  float linv = 1.0f / l;
  float li0 = __shfl(linv, statbase + 0);
  float li1 = __shfl(linv, statbase + 1);
  float li2 = __shfl(linv, statbase + 2);
  float li3 = __shfl(linv, statbase + 3);
  const int orow0 = b * TT + qrow0 + qown;
#pragma unroll
  for (int n = 0; n < 4; ++n) {
    sdp[(size_t)(orow0 + 0) * CC + h * 64 + n * 16 + lr] = o[n][0] * li0;
    sdp[(size_t)(orow0 + 1) * CC + h * 64 + n * 16 + lr] = o[n][1] * li1;
    sdp[(size_t)(orow0 + 2) * CC + h * 64 + n * 16 + lr] = o[n][2] * li2;
    sdp[(size_t)(orow0 + 3) * CC + h * 64 + n * 16 + lr] = o[n][3] * li3;
  }
}

// ---------------- residual + LayerNorm, in-place on io (f32 sdp -> f32 out) ----------------
__global__ __launch_bounds__(256) void k_ln(const float* __restrict__ x,
                                            const float* __restrict__ gamma,
                                            const float* __restrict__ beta,
                                            float* io) {
  __shared__ float red[2][4];
  const int row = blockIdx.x;
  const int tid = threadIdx.x;
  const int i0 = tid * 4;
  float4 xv = *reinterpret_cast<const float4*>(x + (size_t)row * CC + i0);
  float4 sv = *reinterpret_cast<const float4*>(io + (size_t)row * CC + i0);
  float y[4] = {xv.x + sv.x, xv.y + sv.y, xv.z + sv.z, xv.w + sv.w};
  float s = y[0] + y[1] + y[2] + y[3];
  float s2 = y[0] * y[0] + y[1] * y[1] + y[2] * y[2] + y[3] * y[3];
#pragma unroll
  for (int msk = 1; msk < 64; msk <<= 1) {
    s += __shfl_xor(s, msk);
    s2 += __shfl_xor(s2, msk);
  }
  const int wid = tid >> 6;
  if ((tid & 63) == 0) { red[0][wid] = s; red[1][wid] = s2; }
  __syncthreads();
  s = red[0][0] + red[0][1] + red[0][2] + red[0][3];
  s2 = red[1][0] + red[1][1] + red[1][2] + red[1][3];
  float mean = s * (1.0f / CC);
  float var = s2 * (1.0f / CC) - mean * mean;
  float rstd = rsqrtf(var + 1e-6f);
  float4 r;
  r.x = (y[0] - mean) * rstd * gamma[i0 + 0] + beta[i0 + 0];
  r.y = (y[1] - mean) * rstd * gamma[i0 + 1] + beta[i0 + 1];
  r.z = (y[2] - mean) * rstd * gamma[i0 + 2] + beta[i0 + 2];
  r.w = (y[3] - mean) * rstd * gamma[i0 + 3] + beta[i0 + 3];
  *reinterpret_cast<float4*>(io + (size_t)row * CC + i0) = r;
}

extern "C" void kernel_launch(void* const* d_in, const int* in_sizes, int n_in,
                              void* d_out, int out_size, void* d_ws, size_t ws_size,
                              hipStream_t stream) {
  const float* x     = (const float*)d_in[0];
  const float* W1    = (const float*)d_in[1];
  const float* b1    = (const float*)d_in[2];
  const float* gamma = (const float*)d_in[3];
  const float* beta  = (const float*)d_in[4];

  // Memory plan: qkv bf16 (25.2 MB) is the ONLY d_ws user.
  // d_out (f32, 16.78 MB) doubles as scratch: W1t bf16 (dead after GEMM),
  // then sdp f32 (fully overwritten by k_attn), then LN in-place. Output f32.
  unsigned short* qkv = (unsigned short*)d_ws;
  unsigned short* w1t = (unsigned short*)d_out;
  float*          sdp = (float*)d_out;

  k_tr_w1<<<dim3(CC / 32, N3C / 32), 256, 0, stream>>>(W1, w1t);
  k_qkv_gemm<<<dim3(MROWS / 128, N3C / 128), 256, 0, stream>>>(x, w1t, b1, qkv);
  k_attn<<<2 * 16 * (TT / 64), 256, 0, stream>>>(qkv, sdp);
  k_ln<<<MROWS, 256, 0, stream>>>(x, gamma, beta, sdp);
}

// Round 6
// 147.697 us; speedup vs baseline: 1.6982x; 1.1769x over previous
//
#include <hip/hip_runtime.h>
#include <hip/hip_bf16.h>

// Problem constants (B=2, T=2048, C=1024, H=16, hd=64)
#define TT    2048
#define CC    1024
#define N3C   3072
#define MROWS 4096   // B*T

typedef __attribute__((ext_vector_type(8))) short short8;
typedef __attribute__((ext_vector_type(4))) float floatx4;

#define MAX3(a, b, c) fmaxf(fmaxf((a), (b)), (c))

static __device__ __forceinline__ unsigned short f2bf(float f) {
  union { float f; unsigned u; } v; v.f = f;
  return (unsigned short)((v.u + 0x7fffu + ((v.u >> 16) & 1u)) >> 16);
}
static __device__ __forceinline__ unsigned cvt_pk_bf16(float lo, float hi) {
  unsigned r;
  asm("v_cvt_pk_bf16_f32 %0, %1, %2" : "=v"(r) : "v"(lo), "v"(hi));
  return r;
}
static __device__ __forceinline__ float fast_exp2(float x) {
  float r;
  asm("v_exp_f32 %0, %1" : "=v"(r) : "v"(x));
  return r;
}

// ---------------- convert x f32 -> bf16 (xb lives in d_out scratch) ----------------
__global__ __launch_bounds__(256) void k_cvt_x(const float* __restrict__ x,
                                               unsigned short* __restrict__ xb) {
  int i = (blockIdx.x * 256 + threadIdx.x) * 8;
  float4 f0 = *reinterpret_cast<const float4*>(x + i);
  float4 f1 = *reinterpret_cast<const float4*>(x + i + 4);
  union { unsigned u[4]; short8 v; } pk;
  pk.u[0] = cvt_pk_bf16(f0.x, f0.y);
  pk.u[1] = cvt_pk_bf16(f0.z, f0.w);
  pk.u[2] = cvt_pk_bf16(f1.x, f1.y);
  pk.u[3] = cvt_pk_bf16(f1.z, f1.w);
  *reinterpret_cast<short8*>(xb + i) = pk.v;
}

// ---------------- transpose W1 [1024][3072] -> W1t bf16 [3072][1024] ----------------
__global__ __launch_bounds__(256) void k_tr_w1(const float* __restrict__ w,
                                               unsigned short* __restrict__ wt) {
  __shared__ float tile[32][33];
  int k0 = blockIdx.x * 32;   // over K=1024
  int n0 = blockIdx.y * 32;   // over N=3072
  int tx = threadIdx.x & 31;
  int ty = threadIdx.x >> 5;  // 0..7
#pragma unroll
  for (int j = 0; j < 4; ++j)
    tile[ty + 8 * j][tx] = w[(size_t)(k0 + ty + 8 * j) * N3C + n0 + tx];
  __syncthreads();
#pragma unroll
  for (int j = 0; j < 4; ++j)
    wt[(size_t)(n0 + ty + 8 * j) * CC + k0 + tx] = f2bf(tile[tx][ty + 8 * j]);
}

// ---------------- QKV GEMM: xb[4096,1024](bf16) x W1t + b1 -> qkv bf16 ----------------
// 128x128 tile, BK=64, 4 waves. Both operands staged via global_load_lds (16B).
// Q columns (col < CC) pre-scaled by 1/(sqrt(1024)*ln2): attention works in log2 domain.
__global__ __launch_bounds__(256) void k_qkv_gemm(const unsigned short* __restrict__ xb,
                                                  const unsigned short* __restrict__ wt,
                                                  const float* __restrict__ b1,
                                                  unsigned short* __restrict__ qkv) {
  __shared__ unsigned short lA[128 * 64];
  __shared__ unsigned short lB[128 * 64];
  const int tid = threadIdx.x;
  const int bm = blockIdx.x;       // 0..31
  const int bn = blockIdx.y;       // 0..23
  const int wid = tid >> 6, lane = tid & 63;
  const int wr = wid >> 1, wc = wid & 1;
  const int lr = lane & 15;
  const int lg = lane >> 4;
  const int lk = lg * 8;

  floatx4 acc[4][4] = {};

  for (int kt = 0; kt < CC; kt += 64) {
#pragma unroll
    for (int c = 0; c < 4; ++c) {
      int eo = c * 2048 + tid * 8;         // element offset in [128][64] tile
      int row = eo >> 6, col = eo & 63;
      const unsigned short* ga = xb + (size_t)(bm * 128 + row) * CC + kt + col;
      __builtin_amdgcn_global_load_lds((const __attribute__((address_space(1))) void*)ga,
                                       (__attribute__((address_space(3))) void*)(lA + eo), 16, 0, 0);
      const unsigned short* gb = wt + (size_t)(bn * 128 + row) * CC + kt + col;
      __builtin_amdgcn_global_load_lds((const __attribute__((address_space(1))) void*)gb,
                                       (__attribute__((address_space(3))) void*)(lB + eo), 16, 0, 0);
    }
    __syncthreads();
#pragma unroll
    for (int ks = 0; ks < 2; ++ks) {
      short8 a[4], b[4];
#pragma unroll
      for (int m = 0; m < 4; ++m)
        a[m] = *reinterpret_cast<const short8*>(lA + (wr * 64 + m * 16 + lr) * 64 + ks * 32 + lk);
#pragma unroll
      for (int n = 0; n < 4; ++n)
        b[n] = *reinterpret_cast<const short8*>(lB + (wc * 64 + n * 16 + lr) * 64 + ks * 32 + lk);
#pragma unroll
      for (int m = 0; m < 4; ++m)
#pragma unroll
        for (int n = 0; n < 4; ++n)
          acc[m][n] = __builtin_amdgcn_mfma_f32_16x16x32_bf16(a[m], b[n], acc[m][n], 0, 0, 0);
    }
    __syncthreads();
  }

  const int rowb = bm * 128 + wr * 64;
  const int colb = bn * 128 + wc * 64;
#pragma unroll
  for (int n = 0; n < 4; ++n) {
    int col = colb + n * 16 + lr;
    float bias = b1[col];
    // Q: fold 1/sqrt(d_model) AND 1/ln2 (log2-domain softmax) = 0.03125/ln2
    float scl = (col < CC) ? 0.045084372f : 1.0f;
#pragma unroll
    for (int m = 0; m < 4; ++m)
#pragma unroll
      for (int r = 0; r < 4; ++r) {
        int row = rowb + m * 16 + lg * 4 + r;
        qkv[(size_t)row * N3C + col] = f2bf((acc[m][n][r] + bias) * scl);
      }
  }
}

// ---------------- Flash attention: qkv bf16 -> sdp f32 [4096][1024] (in d_out) ----------------
// block = 64 q-rows of one (b,h); 4 waves x 16 rows; KV tiles of 64.
// Swapped QK^T (S^T = K Q^T, log2 domain); per-lane softmax; in-register P transpose.
// V staged as key-PAIR b32 writes (bank-conflict-free).
__global__ __launch_bounds__(256) void k_attn(const unsigned short* __restrict__ qkv,
                                              float* __restrict__ sdp) {
  __shared__ unsigned short lK[2][64 * 64];
  __shared__ unsigned short lVt[2][64 * 64];   // transposed: [hd][key], swizzled

  const int tid = threadIdx.x;
  const int lane = tid & 63, wid = tid >> 6;
  const int lr = lane & 15;
  const int lg = lane >> 4;          // 0..3
  const int lk = lg * 8;
  const int swm = (lr & 7) << 3;     // read-side swizzle mask

  const int bid = blockIdx.x;
  const int qb = bid & 31;
  const int h  = (bid >> 5) & 15;
  const int b  = bid >> 9;

  const int qrow0 = qb * 64 + wid * 16;
  const size_t qbase = ((size_t)(b * TT + qrow0 + lr)) * N3C + h * 64;

  short8 aq[2];
  aq[0] = *reinterpret_cast<const short8*>(qkv + qbase + lk);
  aq[1] = *reinterpret_cast<const short8*>(qkv + qbase + 32 + lk);

  floatx4 o[4] = {};
  float m = -1e30f, l = 0.f;   // stats for query q = lr (log2 domain)

  // shfl source lanes for the P exchange (same lr, different lg group)
  const int srcA = ((2 * lg) & 3) * 16 + lr;
  const int srcB = ((2 * lg + 1) & 3) * 16 + lr;
  const int lg2 = lg >> 1;
  const int qown = lg * 4;                 // o-domain q base (rows qown..qown+3)
  const int statbase = (lane & 48) + qown; // lane holding stats for q=qown+r: statbase+r

  // K staging geometry (global source pre-swizzled, LDS dest linear)
  const int keo0 = tid * 8;
  const int krow0 = keo0 >> 6, kcol0 = (keo0 & 63) ^ ((krow0 & 7) << 3);
  const int keo1 = 2048 + tid * 8;
  const int krow1 = keo1 >> 6, kcol1 = (keo1 & 63) ^ ((krow1 & 7) << 3);
  const size_t kbase = (size_t)(b * TT) * N3C + CC + h * 64;

  // V staging geometry: thread handles keys (2kp, 2kp+1) x 8 d-values (db*8..+7)
  const int kp = tid & 31;
  const int db = tid >> 5;
  const size_t vbase = ((size_t)(b * TT + 2 * kp)) * N3C + 2 * CC + h * 64 + db * 8;

  // ---- prologue: stage tile 0 ----
  {
    const unsigned short* g0 = qkv + kbase + (size_t)krow0 * N3C + kcol0;
    __builtin_amdgcn_global_load_lds((const __attribute__((address_space(1))) void*)g0,
                                     (__attribute__((address_space(3))) void*)(&lK[0][0] + keo0), 16, 0, 0);
    const unsigned short* g1 = qkv + kbase + (size_t)krow1 * N3C + kcol1;
    __builtin_amdgcn_global_load_lds((const __attribute__((address_space(1))) void*)g1,
                                     (__attribute__((address_space(3))) void*)(&lK[0][0] + keo1), 16, 0, 0);
    short8 v0 = *reinterpret_cast<const short8*>(qkv + vbase);
    short8 v1 = *reinterpret_cast<const short8*>(qkv + vbase + N3C);
#pragma unroll
    for (int j = 0; j < 8; ++j) {
      int rr = db * 8 + j;
      int col0 = (2 * kp) ^ (j << 3);
      unsigned wrd = ((unsigned)(unsigned short)v0[j]) | (((unsigned)(unsigned short)v1[j]) << 16);
      *reinterpret_cast<unsigned*>(&lVt[0][rr * 64 + col0]) = wrd;
    }
  }
  __syncthreads();

  for (int kt = 0; kt < TT / 64; ++kt) {
    const int cur = kt & 1;
    short8 nv0, nv1;
    if (kt < TT / 64 - 1) {
      const size_t koff = kbase + (size_t)((kt + 1) * 64) * N3C;
      const unsigned short* g0 = qkv + koff + (size_t)krow0 * N3C + kcol0;
      __builtin_amdgcn_global_load_lds((const __attribute__((address_space(1))) void*)g0,
                                       (__attribute__((address_space(3))) void*)(&lK[cur ^ 1][0] + keo0), 16, 0, 0);
      const unsigned short* g1 = qkv + koff + (size_t)krow1 * N3C + kcol1;
      __builtin_amdgcn_global_load_lds((const __attribute__((address_space(1))) void*)g1,
                                       (__attribute__((address_space(3))) void*)(&lK[cur ^ 1][0] + keo1), 16, 0, 0);
      const unsigned short* gv = qkv + vbase + (size_t)((kt + 1) * 64) * N3C;
      nv0 = *reinterpret_cast<const short8*>(gv);
      nv1 = *reinterpret_cast<const short8*>(gv + N3C);
    }

    // ---- S^T = K Q^T : lane holds S[key = n*16+lg*4+r][q = lr] (log2 domain) ----
    floatx4 s[4];
    __builtin_amdgcn_s_setprio(1);
#pragma unroll
    for (int n = 0; n < 4; ++n) {
      floatx4 z = {};
#pragma unroll
      for (int ks = 0; ks < 2; ++ks) {
        short8 bk = *reinterpret_cast<const short8*>(
            &lK[cur][0] + (n * 16 + lr) * 64 + ((ks * 32 + lk) ^ swm));
        z = __builtin_amdgcn_mfma_f32_16x16x32_bf16(bk, aq[ks], z, 0, 0, 0);
      }
      s[n] = z;
    }
    __builtin_amdgcn_s_setprio(0);

    // ---- per-lane online softmax (base-2) over this tile's 64 keys for q=lr ----
    float a0 = MAX3(s[0][0], s[0][1], s[0][2]);
    float a1 = MAX3(s[0][3], s[1][0], s[1][1]);
    float a2 = MAX3(s[1][2], s[1][3], s[2][0]);
    float a3 = MAX3(s[2][1], s[2][2], s[2][3]);
    float a4 = MAX3(s[3][0], s[3][1], s[3][2]);
    float pmax = fmaxf(MAX3(a0, a1, a2), MAX3(a3, a4, s[3][3]));
    pmax = fmaxf(pmax, __shfl_xor(pmax, 16));
    pmax = fmaxf(pmax, __shfl_xor(pmax, 32));

    if (__any(pmax > m + 11.5f)) {        // defer-max (2^11.5 ~ e^8 headroom)
      float mnew = fmaxf(m, pmax);
      float alpha = fast_exp2(m - mnew);
      m = mnew;
      l *= alpha;
      float b0 = __shfl(alpha, statbase + 0);
      float b1_ = __shfl(alpha, statbase + 1);
      float b2 = __shfl(alpha, statbase + 2);
      float b3 = __shfl(alpha, statbase + 3);
#pragma unroll
      for (int n = 0; n < 4; ++n) {
        o[n][0] *= b0; o[n][1] *= b1_; o[n][2] *= b2; o[n][3] *= b3;
      }
    }

    float p[4][4], lsum = 0.f;
#pragma unroll
    for (int n = 0; n < 4; ++n)
#pragma unroll
      for (int r = 0; r < 4; ++r) {
        p[n][r] = fast_exp2(s[n][r] - m);
        lsum += p[n][r];
      }
    lsum += __shfl_xor(lsum, 16);
    lsum += __shfl_xor(lsum, 32);
    l += lsum;

    // ---- pack P to bf16 pairs: w[n][mi] = {lo=p[n][2mi], hi=p[n][2mi+1]} ----
    unsigned w[4][2];
#pragma unroll
    for (int n = 0; n < 4; ++n)
#pragma unroll
      for (int mi = 0; mi < 2; ++mi)
        w[n][mi] = cvt_pk_bf16(p[n][2 * mi], p[n][2 * mi + 1]);

    // ---- in-register transpose to A-fragment words fw[ks][jp] ----
    // lane(lg,lr) needs w[2ks+lg2][M] from srcA (->fw[ks][M]) and srcB (->fw[ks][M+2])
    unsigned fw[2][4];
#pragma unroll
    for (int ks2 = 0; ks2 < 2; ++ks2)
#pragma unroll
      for (int M = 0; M < 2; ++M) {
        int g0A = __shfl((int)w[2 * ks2][M], srcA);
        int g0B = __shfl((int)w[2 * ks2][M], srcB);
        int g1A = __shfl((int)w[2 * ks2 + 1][M], srcA);
        int g1B = __shfl((int)w[2 * ks2 + 1][M], srcB);
        fw[ks2][M]     = (unsigned)(lg2 ? g1A : g0A);
        fw[ks2][M + 2] = (unsigned)(lg2 ? g1B : g0B);
      }
    union { unsigned u[4]; short8 v; } apc0, apc1;
#pragma unroll
    for (int j = 0; j < 4; ++j) { apc0.u[j] = fw[0][j]; apc1.u[j] = fw[1][j]; }

    // ---- PV: o[q=lg*4+r][d=n*16+lr] += P^T-frag x V^T rows ----
    __builtin_amdgcn_s_setprio(1);
#pragma unroll
    for (int n = 0; n < 4; ++n) {
      short8 bv0 = *reinterpret_cast<const short8*>(
          &lVt[cur][0] + (n * 16 + lr) * 64 + ((0 + lk) ^ swm));
      o[n] = __builtin_amdgcn_mfma_f32_16x16x32_bf16(apc0.v, bv0, o[n], 0, 0, 0);
      short8 bv1 = *reinterpret_cast<const short8*>(
          &lVt[cur][0] + (n * 16 + lr) * 64 + ((32 + lk) ^ swm));
      o[n] = __builtin_amdgcn_mfma_f32_16x16x32_bf16(apc1.v, bv1, o[n], 0, 0, 0);
    }
    __builtin_amdgcn_s_setprio(0);

    // ---- write next V tile (b32 key-pairs, conflict-free), then one barrier ----
    if (kt < TT / 64 - 1) {
#pragma unroll
      for (int j = 0; j < 8; ++j) {
        int rr = db * 8 + j;
        int col0 = (2 * kp) ^ (j << 3);
        unsigned wrd = ((unsigned)(unsigned short)nv0[j]) | (((unsigned)(unsigned short)nv1[j]) << 16);
        *reinterpret_cast<unsigned*>(&lVt[cur ^ 1][rr * 64 + col0]) = wrd;
      }
    }
    __syncthreads();  // drains vmcnt (K stage) + makes V writes visible
  }

  // epilogue: broadcast 1/l to o-domain, write merged-head sdp (f32)
  float linv = 1.0f / l;
  float li0 = __shfl(linv, statbase + 0);
  float li1 = __shfl(linv, statbase + 1);
  float li2 = __shfl(linv, statbase + 2);
  float li3 = __shfl(linv, statbase + 3);
  const int orow0 = b * TT + qrow0 + qown;
#pragma unroll
  for (int n = 0; n < 4; ++n) {
    sdp[(size_t)(orow0 + 0) * CC + h * 64 + n * 16 + lr] = o[n][0] * li0;
    sdp[(size_t)(orow0 + 1) * CC + h * 64 + n * 16 + lr] = o[n][1] * li1;
    sdp[(size_t)(orow0 + 2) * CC + h * 64 + n * 16 + lr] = o[n][2] * li2;
    sdp[(size_t)(orow0 + 3) * CC + h * 64 + n * 16 + lr] = o[n][3] * li3;
  }
}

// ---------------- residual + LayerNorm, in-place on io (f32 sdp -> f32 out) ----------------
__global__ __launch_bounds__(256) void k_ln(const float* __restrict__ x,
                                            const float* __restrict__ gamma,
                                            const float* __restrict__ beta,
                                            float* io) {
  __shared__ float red[2][4];
  const int row = blockIdx.x;
  const int tid = threadIdx.x;
  const int i0 = tid * 4;
  float4 xv = *reinterpret_cast<const float4*>(x + (size_t)row * CC + i0);
  float4 sv = *reinterpret_cast<const float4*>(io + (size_t)row * CC + i0);
  float y[4] = {xv.x + sv.x, xv.y + sv.y, xv.z + sv.z, xv.w + sv.w};
  float s = y[0] + y[1] + y[2] + y[3];
  float s2 = y[0] * y[0] + y[1] * y[1] + y[2] * y[2] + y[3] * y[3];
#pragma unroll
  for (int msk = 1; msk < 64; msk <<= 1) {
    s += __shfl_xor(s, msk);
    s2 += __shfl_xor(s2, msk);
  }
  const int wid = tid >> 6;
  if ((tid & 63) == 0) { red[0][wid] = s; red[1][wid] = s2; }
  __syncthreads();
  s = red[0][0] + red[0][1] + red[0][2] + red[0][3];
  s2 = red[1][0] + red[1][1] + red[1][2] + red[1][3];
  float mean = s * (1.0f / CC);
  float var = s2 * (1.0f / CC) - mean * mean;
  float rstd = rsqrtf(var + 1e-6f);
  float4 r;
  r.x = (y[0] - mean) * rstd * gamma[i0 + 0] + beta[i0 + 0];
  r.y = (y[1] - mean) * rstd * gamma[i0 + 1] + beta[i0 + 1];
  r.z = (y[2] - mean) * rstd * gamma[i0 + 2] + beta[i0 + 2];
  r.w = (y[3] - mean) * rstd * gamma[i0 + 3] + beta[i0 + 3];
  *reinterpret_cast<float4*>(io + (size_t)row * CC + i0) = r;
}

extern "C" void kernel_launch(void* const* d_in, const int* in_sizes, int n_in,
                              void* d_out, int out_size, void* d_ws, size_t ws_size,
                              hipStream_t stream) {
  const float* x     = (const float*)d_in[0];
  const float* W1    = (const float*)d_in[1];
  const float* b1    = (const float*)d_in[2];
  const float* gamma = (const float*)d_in[3];
  const float* beta  = (const float*)d_in[4];

  // Memory plan: qkv bf16 (25.2 MB) is the ONLY d_ws user (ws_size lower bound
  // established empirically). d_out (16.78 MB f32) doubles as scratch:
  //   [0, 6.29MB)      W1t bf16   (dead after GEMM)
  //   [6.29, 14.68MB)  xb bf16    (dead after GEMM)
  // then k_attn overwrites all of d_out with sdp f32; LN runs in-place.
  unsigned short* qkv = (unsigned short*)d_ws;
  unsigned short* w1t = (unsigned short*)d_out;
  unsigned short* xb  = (unsigned short*)((char*)d_out + 6291456);
  float*          sdp = (float*)d_out;

  k_cvt_x<<<MROWS * CC / (256 * 8), 256, 0, stream>>>(x, xb);
  k_tr_w1<<<dim3(CC / 32, N3C / 32), 256, 0, stream>>>(W1, w1t);
  k_qkv_gemm<<<dim3(MROWS / 128, N3C / 128), 256, 0, stream>>>(xb, w1t, b1, qkv);
  k_attn<<<2 * 16 * (TT / 64), 256, 0, stream>>>(qkv, sdp);
  k_ln<<<MROWS, 256, 0, stream>>>(x, gamma, beta, sdp);
}